// Round 6
// baseline (212.586 us; speedup 1.0000x reference)
//
#include <hip/hip_runtime.h>
#include <hip/hip_bf16.h>
#include <math.h>

typedef __bf16 bf16_t;
typedef __bf16 bf16x8 __attribute__((ext_vector_type(8)));
typedef float f32x4 __attribute__((ext_vector_type(4)));

constexpr int SS = 4096;
constexpr int DD = 1024;
constexpr int HH = 64;

#if __has_builtin(__builtin_amdgcn_exp2f)
#define EXP2F __builtin_amdgcn_exp2f
#else
#define EXP2F exp2f
#endif

static __device__ __forceinline__ f32x4 mfma16(bf16x8 a, bf16x8 b, f32x4 c) {
  return __builtin_amdgcn_mfma_f32_16x16x32_bf16(a, b, c, 0, 0, 0);
}

// ---------------- kernel 0: W -> Wt bf16 (coalesced via LDS transpose) -------------
__global__ __launch_bounds__(256) void prep_w(const float* __restrict__ wq,
                                              const float* __restrict__ wk,
                                              const float* __restrict__ wv,
                                              bf16_t* __restrict__ wt) {
  __shared__ float ls[64 * 68];
  int tid = threadIdx.x;
  int sel = blockIdx.x >> 4, kb = blockIdx.x & 15, k0 = kb * 64;
  const float* src = (sel == 0) ? wq : ((sel == 1) ? wk : wv);
  int bn = sel * 64;
#pragma unroll
  for (int i = 0; i < 4; ++i) {
    int e = tid + i * 256;
    int r = e >> 4, c4 = (e & 15) * 4;
    *(float4*)&ls[r * 68 + c4] = *(const float4*)(src + (size_t)(k0 + r) * 64 + c4);
  }
  __syncthreads();
#pragma unroll
  for (int j = 0; j < 2; ++j) {
    int e = tid + j * 256;
    int n = e >> 3, kg = e & 7;
    bf16x8 v;
#pragma unroll
    for (int t = 0; t < 8; ++t) v[t] = (bf16_t)ls[(kg * 8 + t) * 68 + n];
    *(bf16x8*)(wt + (size_t)(bn + n) * 1024 + k0 + kg * 8) = v;
  }
}

// ---------------- kernel 1: QKV GEMM — M=32 x N=192, 512 WGs, dbuf (R1-proven) -----
__global__ __launch_bounds__(256) void gemm_qkv(const float* __restrict__ x,
                                                const bf16_t* __restrict__ wt,
                                                bf16_t* __restrict__ qo,
                                                bf16_t* __restrict__ ko,
                                                bf16_t* __restrict__ vto) {
  __shared__ bf16_t xs[2][32 * 64];    // 8 KB dbuf, XOR-swizzled
  __shared__ bf16_t wsh[2][192 * 64];  // 48 KB dbuf, XOR-swizzled
  int tid = threadIdx.x;
  int wave = tid >> 6, lane = tid & 63, quad = lane >> 4, ml = lane & 15;
  int m0 = blockIdx.x * 32;
  int mtile = wave >> 1;          // 0..1 : which 16-row block
  int nt0 = (wave & 1) * 6;       // 0 or 6 : first of six 16-col n-tiles

  f32x4 acc[6];
#pragma unroll
  for (int i = 0; i < 6; ++i) acc[i] = (f32x4){0.f, 0.f, 0.f, 0.f};

  int xrow = tid >> 3, xseg = tid & 7;  // 32 rows x 8 segs of 8 f32
  float4 xr[2];
  bf16x8 wr[6];

  auto load_g = [&](int k0) {
    const float* p = x + (size_t)(m0 + xrow) * DD + k0 + xseg * 8;
    xr[0] = *(const float4*)p;
    xr[1] = *(const float4*)(p + 4);
#pragma unroll
    for (int i = 0; i < 6; ++i) {
      int c = tid + i * 256;
      int r = c >> 3, cc = c & 7;
      wr[i] = *(const bf16x8*)(wt + (size_t)r * DD + k0 + cc * 8);
    }
  };
  auto store_lds = [&](int bf) {
    bf16x8 v0;
    v0[0] = (bf16_t)xr[0].x; v0[1] = (bf16_t)xr[0].y;
    v0[2] = (bf16_t)xr[0].z; v0[3] = (bf16_t)xr[0].w;
    v0[4] = (bf16_t)xr[1].x; v0[5] = (bf16_t)xr[1].y;
    v0[6] = (bf16_t)xr[1].z; v0[7] = (bf16_t)xr[1].w;
    int cc0 = xseg ^ (xrow & 7);
    *(bf16x8*)&xs[bf][xrow * 64 + cc0 * 8] = v0;
#pragma unroll
    for (int i = 0; i < 6; ++i) {
      int c = tid + i * 256;
      int r = c >> 3, cc = c & 7;
      *(bf16x8*)&wsh[bf][r * 64 + ((cc ^ (r & 7)) * 8)] = wr[i];
    }
  };

  load_g(0);
  store_lds(0);
  load_g(64);
  __syncthreads();
  for (int it = 0; it < 16; ++it) {
    int bf = it & 1;
#pragma unroll
    for (int s = 0; s < 2; ++s) {
      int rchunk = ((s * 4 + quad) ^ (ml & 7)) * 8;
      bf16x8 a = *(const bf16x8*)&xs[bf][(mtile * 16 + ml) * 64 + rchunk];
#pragma unroll
      for (int i = 0; i < 6; ++i) {
        bf16x8 bfr = *(const bf16x8*)&wsh[bf][((nt0 + i) * 16 + ml) * 64 + rchunk];
        acc[i] = mfma16(a, bfr, acc[i]);
      }
    }
    if (it < 15) {
      store_lds(1 - bf);
      if (it < 14) load_g((it + 2) * 64);
      __syncthreads();
    }
  }

  int b = m0 >> 12;
  int sr = m0 & 4095;
  const float QSCALE = 0.18033688011112042f;  // log2(e)/sqrt(64)
  bf16_t* vls = (bf16_t*)wsh;                 // overlay: 64 h x 40 stride = 5 KB
#pragma unroll
  for (int i = 0; i < 6; ++i) {
    int col = (wave & 1) * 96 + i * 16 + ml;
#pragma unroll
    for (int r = 0; r < 4; ++r) {
      int lrow = mtile * 16 + quad * 4 + r;
      size_t grow = (size_t)b * SS + sr + lrow;
      if (col < 64) qo[grow * HH + col] = (bf16_t)(acc[i][r] * QSCALE);
      else if (col < 128) ko[grow * HH + (col - 64)] = (bf16_t)(acc[i][r]);
      else vls[(col - 128) * 40 + lrow] = (bf16_t)(acc[i][r]);
    }
  }
  __syncthreads();
  {
    int h = tid >> 2, sg = tid & 3;  // 64 heads x 4 segs of 8 keys
    *(bf16x8*)(vto + ((size_t)b * HH + h) * SS + sr + sg * 8) =
        *(const bf16x8*)&vls[h * 40 + sg * 8];
  }
}

// ---------------- kernel 2: flash attention, 16 KB LDS -> 8 WG/CU ------------------
// P is packed into Kl's space (Kl is dead after QK^T) instead of a dedicated 8 KB
// Pl buffer: LDS 24->16 KB, occupancy 6->8 WG/CU (32 waves, 100%). Costs one extra
// barrier per tile (bar_C: all waves' QK reads of Kl must finish before P-pack).
// __launch_bounds__(256,8) pins VGPR<=64 so the wave cap, not VGPRs, binds.
// grid 1376 = 4b x 344 jobs. j = 343-(bid>>2) longest-first, b = bid&3.
__global__ __launch_bounds__(256, 8) void attn_partial(const bf16_t* __restrict__ qg,
                                                       const bf16_t* __restrict__ kg,
                                                       const bf16_t* __restrict__ vg,
                                                       float* __restrict__ partO,
                                                       float* __restrict__ lb,
                                                       float* __restrict__ out) {
  __shared__ bf16_t Kl[64 * 64];      // 8 KB [key][h] swizzled; P scratch after QK
  __shared__ bf16_t Vl[64 * 64];      // 8 KB [h][key] swizzled
  int tid = threadIdx.x;
  int wave = tid >> 6, lane = tid & 63, quad = lane >> 4, ml = lane & 15;

  int bid = blockIdx.x;
  int b = bid & 3;
  int j = 343 - (bid >> 2);
  int jt, ch, nch;
  if (j < 8)        { jt = j;                   ch = 0;            nch = 1; }
  else if (j < 24)  { jt = 8  + ((j - 8) >> 1); ch = (j - 8) & 1;  nch = 2; }
  else if (j < 88)  { jt = 16 + ((j - 24) >> 2); ch = (j - 24) & 3; nch = 4; }
  else              { jt = 32 + ((j - 88) >> 3); ch = (j - 88) & 7; nch = 8; }
  int L = (jt + nch) / nch;           // ceil((jt+1)/nch)
  int c0 = ch * L;
  int c1 = c0 + L; if (c1 > jt + 1) c1 = jt + 1;
  int len = c1 - c0;
  bool direct = (nch == 1);
  int slot = b * 336 + (j - 8);       // valid only when !direct
  int q0 = jt * 64;

  const bf16_t* qb = qg + (size_t)b * SS * HH;
  const bf16_t* kb = kg + (size_t)b * SS * HH;
  const bf16_t* vb = vg + (size_t)b * HH * SS;

  int qrow = q0 + wave * 16 + ml;
  bf16x8 aq0 = *(const bf16x8*)(qb + (size_t)qrow * HH + quad * 8);
  bf16x8 aq1 = *(const bf16x8*)(qb + (size_t)qrow * HH + 32 + quad * 8);

  bf16x8 kreg[2], vreg[2];
  int srl = tid >> 3, scc = tid & 7;
  auto load_kv = [&](int kt) {
#pragma unroll
    for (int i = 0; i < 2; ++i) {
      int r = srl + i * 32;
      kreg[i] = *(const bf16x8*)(kb + (size_t)(kt * 64 + r) * HH + scc * 8);
      vreg[i] = *(const bf16x8*)(vb + (size_t)r * SS + kt * 64 + scc * 8);
    }
  };
  auto store_kv = [&]() {
#pragma unroll
    for (int i = 0; i < 2; ++i) {
      int r = srl + i * 32;
      int off = r * 64 + ((scc ^ (r & 7)) * 8);
      *(bf16x8*)&Kl[off] = kreg[i];
      *(bf16x8*)&Vl[off] = vreg[i];
    }
  };

  f32x4 oa[4];
#pragma unroll
  for (int i = 0; i < 4; ++i) oa[i] = (f32x4){0.f, 0.f, 0.f, 0.f};
  float lr[4] = {0.f, 0.f, 0.f, 0.f};

  load_kv(c0);

  for (int i = 0; i < len; ++i) {
    int kt = c0 + i;
    __syncthreads();                    // bar_A: prior iter's P/V reads done
    store_kv();
    __syncthreads();                    // bar_B: staged tile visible
    if (i + 1 < len) load_kv(kt + 1);   // register prefetch hides global latency

    f32x4 sa[4];
#pragma unroll
    for (int nt = 0; nt < 4; ++nt) sa[nt] = (f32x4){0.f, 0.f, 0.f, 0.f};
#pragma unroll
    for (int s = 0; s < 2; ++s) {
      bf16x8 a = s ? aq1 : aq0;
      int rchunk = ((s * 4 + quad) ^ (ml & 7)) * 8;
#pragma unroll
      for (int nt = 0; nt < 4; ++nt) {
        bf16x8 bfr = *(const bf16x8*)&Kl[(nt * 16 + ml) * 64 + rchunk];
        sa[nt] = mfma16(a, bfr, sa[nt]);
      }
    }

    if (kt == jt) {
#pragma unroll
      for (int nt = 0; nt < 4; ++nt) {
        int key = kt * 64 + nt * 16 + ml;
#pragma unroll
        for (int r = 0; r < 4; ++r) {
          int qr = q0 + wave * 16 + quad * 4 + r;
          if (key > qr) sa[nt][r] = -3.38953139e38f;
        }
      }
    }

    // no-max softmax (log2-domain scores bounded; fp32-safe)
#pragma unroll
    for (int r = 0; r < 4; ++r) {
      float p0 = EXP2F(sa[0][r]);
      float p1 = EXP2F(sa[1][r]);
      float p2 = EXP2F(sa[2][r]);
      float p3 = EXP2F(sa[3][r]);
      sa[0][r] = p0; sa[1][r] = p1; sa[2][r] = p2; sa[3][r] = p3;
      lr[r] += (p0 + p1) + (p2 + p3);
    }

    __syncthreads();                    // bar_C: all waves' QK reads of Kl done
    // P: C-layout -> A-layout via per-wave region of Kl (dead after QK)
    bf16_t* Pw = &Kl[wave * 1024];
#pragma unroll
    for (int nt = 0; nt < 4; ++nt) {
#pragma unroll
      for (int r = 0; r < 4; ++r) {
        int row = quad * 4 + r;
        int cc = nt * 2 + (ml >> 3);
        Pw[row * 64 + ((cc ^ (row & 7)) * 8) + (ml & 7)] = (bf16_t)sa[nt][r];
      }
    }
#pragma unroll
    for (int s = 0; s < 2; ++s) {
      int rchunk = ((s * 4 + quad) ^ (ml & 7)) * 8;
      bf16x8 pa = *(const bf16x8*)&Pw[ml * 64 + rchunk];
#pragma unroll
      for (int ht = 0; ht < 4; ++ht) {
        bf16x8 bv = *(const bf16x8*)&Vl[(ht * 16 + ml) * 64 + rchunk];
        oa[ht] = mfma16(pa, bv, oa[ht]);
      }
    }
  }

#pragma unroll
  for (int r = 0; r < 4; ++r) {
    float t = lr[r];
    t += __shfl_xor(t, 1);
    t += __shfl_xor(t, 2);
    t += __shfl_xor(t, 4);
    t += __shfl_xor(t, 8);
    lr[r] = t;
  }

  if (direct) {
#pragma unroll
    for (int r = 0; r < 4; ++r) {
      float inv = 1.0f / lr[r];
      int row = q0 + wave * 16 + quad * 4 + r;
#pragma unroll
      for (int ht = 0; ht < 4; ++ht)
        out[((size_t)b * SS + row) * HH + ht * 16 + ml] = oa[ht][r] * inv;
    }
  } else {
    float* po = partO + (size_t)slot * 4096;
#pragma unroll
    for (int r = 0; r < 4; ++r) {
      int row = wave * 16 + quad * 4 + r;
#pragma unroll
      for (int ht = 0; ht < 4; ++ht)
        po[row * 64 + ht * 16 + ml] = oa[ht][r];
      if (ml == 0) lb[slot * 64 + row] = lr[r];
    }
  }
}

// ---------------- kernel 3: combine — 896 WGs (16 rows/WG), f32x4 per thread -------
// 4x the parallelism of the 224-WG version (3.5 WG/CU): latency-bound partO reads
// now overlap across more waves.
__global__ __launch_bounds__(256) void combine(const float* __restrict__ partO,
                                               const float* __restrict__ lb,
                                               float* __restrict__ out) {
  int bid = blockIdx.x;      // 896 = 224 jobs x 4 row-groups
  int rg = bid & 3;
  int jobid = bid >> 2;      // 0..223 = b(4) x jt(8..63)
  int b = jobid / 56;
  int jt = 8 + (jobid - b * 56);
  int nch, jbase;
  if (jt < 16)      { nch = 2; jbase = 8 + 2 * (jt - 8); }
  else if (jt < 32) { nch = 4; jbase = 24 + 4 * (jt - 16); }
  else              { nch = 8; jbase = 88 + 8 * (jt - 32); }
  int base = b * 336 + (jbase - 8);
  int tid = threadIdx.x;
  int row = rg * 16 + (tid >> 4);   // 16 rows per WG
  int seg = tid & 15;               // 16 f32x4 segments = 64 cols

  float l = 0.f;
  f32x4 o = (f32x4){0.f, 0.f, 0.f, 0.f};
  for (int c = 0; c < nch; ++c) {
    l += lb[(base + c) * 64 + row];
    o += *(const f32x4*)(partO + (size_t)(base + c) * 4096 + row * 64 + seg * 4);
  }
  float inv = 1.0f / l;
  *(f32x4*)(out + (((size_t)b * SS) + jt * 64 + row) * HH + seg * 4) = o * inv;
}

// ---------------- host ----------------
extern "C" void kernel_launch(void* const* d_in, const int* in_sizes, int n_in,
                              void* d_out, int out_size, void* d_ws, size_t ws_size,
                              hipStream_t stream) {
  const float* x  = (const float*)d_in[0];
  const float* wq = (const float*)d_in[1];
  const float* wk = (const float*)d_in[2];
  const float* wv = (const float*)d_in[3];
  float* out = (float*)d_out;

  char* wsb = (char*)d_ws;
  bf16_t* wt  = (bf16_t*)wsb;                    // 384 KB
  bf16_t* q   = (bf16_t*)(wsb + 524288);         // 2 MB
  bf16_t* k   = (bf16_t*)(wsb + 2621440);        // 2 MB
  bf16_t* vt  = (bf16_t*)(wsb + 4718592);        // 2 MB
  float*  po  = (float*)(wsb + 6815744);         // 21.5 MB (1344 slots x 16 KB)
  float*  lb  = (float*)(wsb + 28835840);        // 344 KB

  prep_w<<<48, 256, 0, stream>>>(wq, wk, wv, wt);
  gemm_qkv<<<512, 256, 0, stream>>>(x, wt, q, k, vt);
  attn_partial<<<1376, 256, 0, stream>>>(q, k, vt, po, lb, out);
  combine<<<896, 256, 0, stream>>>(po, lb, out);
}

// Round 7
// 142.543 us; speedup vs baseline: 1.4914x; 1.4914x over previous
//
#include <hip/hip_runtime.h>
#include <hip/hip_bf16.h>
#include <math.h>

typedef __bf16 bf16_t;
typedef __bf16 bf16x8 __attribute__((ext_vector_type(8)));
typedef float f32x4 __attribute__((ext_vector_type(4)));

constexpr int SS = 4096;
constexpr int DD = 1024;
constexpr int HH = 64;

#if __has_builtin(__builtin_amdgcn_exp2f)
#define EXP2F __builtin_amdgcn_exp2f
#else
#define EXP2F exp2f
#endif

static __device__ __forceinline__ f32x4 mfma16(bf16x8 a, bf16x8 b, f32x4 c) {
  return __builtin_amdgcn_mfma_f32_16x16x32_bf16(a, b, c, 0, 0, 0);
}

// ---------------- kernel 0: W -> Wt bf16 (coalesced via LDS transpose) -------------
__global__ __launch_bounds__(256) void prep_w(const float* __restrict__ wq,
                                              const float* __restrict__ wk,
                                              const float* __restrict__ wv,
                                              bf16_t* __restrict__ wt) {
  __shared__ float ls[64 * 68];
  int tid = threadIdx.x;
  int sel = blockIdx.x >> 4, kb = blockIdx.x & 15, k0 = kb * 64;
  const float* src = (sel == 0) ? wq : ((sel == 1) ? wk : wv);
  int bn = sel * 64;
#pragma unroll
  for (int i = 0; i < 4; ++i) {
    int e = tid + i * 256;
    int r = e >> 4, c4 = (e & 15) * 4;
    *(float4*)&ls[r * 68 + c4] = *(const float4*)(src + (size_t)(k0 + r) * 64 + c4);
  }
  __syncthreads();
#pragma unroll
  for (int j = 0; j < 2; ++j) {
    int e = tid + j * 256;
    int n = e >> 3, kg = e & 7;
    bf16x8 v;
#pragma unroll
    for (int t = 0; t < 8; ++t) v[t] = (bf16_t)ls[(kg * 8 + t) * 68 + n];
    *(bf16x8*)(wt + (size_t)(bn + n) * 1024 + k0 + kg * 8) = v;
  }
}

// ---------------- kernel 1: QKV GEMM — M=32 x N=192, 512 WGs, dbuf (R1-proven) -----
__global__ __launch_bounds__(256) void gemm_qkv(const float* __restrict__ x,
                                                const bf16_t* __restrict__ wt,
                                                bf16_t* __restrict__ qo,
                                                bf16_t* __restrict__ ko,
                                                bf16_t* __restrict__ vto) {
  __shared__ bf16_t xs[2][32 * 64];    // 8 KB dbuf, XOR-swizzled
  __shared__ bf16_t wsh[2][192 * 64];  // 48 KB dbuf, XOR-swizzled
  int tid = threadIdx.x;
  int wave = tid >> 6, lane = tid & 63, quad = lane >> 4, ml = lane & 15;
  int m0 = blockIdx.x * 32;
  int mtile = wave >> 1;          // 0..1 : which 16-row block
  int nt0 = (wave & 1) * 6;       // 0 or 6 : first of six 16-col n-tiles

  f32x4 acc[6];
#pragma unroll
  for (int i = 0; i < 6; ++i) acc[i] = (f32x4){0.f, 0.f, 0.f, 0.f};

  int xrow = tid >> 3, xseg = tid & 7;  // 32 rows x 8 segs of 8 f32
  float4 xr[2];
  bf16x8 wr[6];

  auto load_g = [&](int k0) {
    const float* p = x + (size_t)(m0 + xrow) * DD + k0 + xseg * 8;
    xr[0] = *(const float4*)p;
    xr[1] = *(const float4*)(p + 4);
#pragma unroll
    for (int i = 0; i < 6; ++i) {
      int c = tid + i * 256;
      int r = c >> 3, cc = c & 7;
      wr[i] = *(const bf16x8*)(wt + (size_t)r * DD + k0 + cc * 8);
    }
  };
  auto store_lds = [&](int bf) {
    bf16x8 v0;
    v0[0] = (bf16_t)xr[0].x; v0[1] = (bf16_t)xr[0].y;
    v0[2] = (bf16_t)xr[0].z; v0[3] = (bf16_t)xr[0].w;
    v0[4] = (bf16_t)xr[1].x; v0[5] = (bf16_t)xr[1].y;
    v0[6] = (bf16_t)xr[1].z; v0[7] = (bf16_t)xr[1].w;
    int cc0 = xseg ^ (xrow & 7);
    *(bf16x8*)&xs[bf][xrow * 64 + cc0 * 8] = v0;
#pragma unroll
    for (int i = 0; i < 6; ++i) {
      int c = tid + i * 256;
      int r = c >> 3, cc = c & 7;
      *(bf16x8*)&wsh[bf][r * 64 + ((cc ^ (r & 7)) * 8)] = wr[i];
    }
  };

  load_g(0);
  store_lds(0);
  load_g(64);
  __syncthreads();
  for (int it = 0; it < 16; ++it) {
    int bf = it & 1;
#pragma unroll
    for (int s = 0; s < 2; ++s) {
      int rchunk = ((s * 4 + quad) ^ (ml & 7)) * 8;
      bf16x8 a = *(const bf16x8*)&xs[bf][(mtile * 16 + ml) * 64 + rchunk];
#pragma unroll
      for (int i = 0; i < 6; ++i) {
        bf16x8 bfr = *(const bf16x8*)&wsh[bf][((nt0 + i) * 16 + ml) * 64 + rchunk];
        acc[i] = mfma16(a, bfr, acc[i]);
      }
    }
    if (it < 15) {
      store_lds(1 - bf);
      if (it < 14) load_g((it + 2) * 64);
      __syncthreads();
    }
  }

  int b = m0 >> 12;
  int sr = m0 & 4095;
  const float QSCALE = 0.18033688011112042f;  // log2(e)/sqrt(64)
  bf16_t* vls = (bf16_t*)wsh;                 // overlay: 64 h x 40 stride = 5 KB
#pragma unroll
  for (int i = 0; i < 6; ++i) {
    int col = (wave & 1) * 96 + i * 16 + ml;
#pragma unroll
    for (int r = 0; r < 4; ++r) {
      int lrow = mtile * 16 + quad * 4 + r;
      size_t grow = (size_t)b * SS + sr + lrow;
      if (col < 64) qo[grow * HH + col] = (bf16_t)(acc[i][r] * QSCALE);
      else if (col < 128) ko[grow * HH + (col - 64)] = (bf16_t)(acc[i][r]);
      else vls[(col - 128) * 40 + lrow] = (bf16_t)(acc[i][r]);
    }
  }
  __syncthreads();
  {
    int h = tid >> 2, sg = tid & 3;  // 64 heads x 4 segs of 8 keys
    *(bf16x8*)(vto + ((size_t)b * HH + h) * SS + sr + sg * 8) =
        *(const bf16x8*)&vls[h * 40 + sg * 8];
  }
}

// ---------------- kernel 2: flash attention, 24 KB LDS (6 WG/CU) — R1-proven -------
// grid 1376 = 4b x 344 jobs. j = 343-(bid>>2) longest-first, b = bid&3.
// j<8: jt=j direct. [8,24): jt=8+((j-8)>>1), nch2. [24,88): jt=16+((j-24)>>2), nch4.
// [88,344): jt=32+((j-88)>>3), nch8.
__global__ __launch_bounds__(256) void attn_partial(const bf16_t* __restrict__ qg,
                                                    const bf16_t* __restrict__ kg,
                                                    const bf16_t* __restrict__ vg,
                                                    float* __restrict__ partO,
                                                    float* __restrict__ lb,
                                                    float* __restrict__ out) {
  __shared__ bf16_t Kl[64 * 64];      // 8 KB [key][h] swizzled
  __shared__ bf16_t Vl[64 * 64];      // 8 KB [h][key] swizzled
  __shared__ bf16_t Pl[4][16 * 64];   // 8 KB per-wave scratch
  int tid = threadIdx.x;
  int wave = tid >> 6, lane = tid & 63, quad = lane >> 4, ml = lane & 15;

  int bid = blockIdx.x;
  int b = bid & 3;
  int j = 343 - (bid >> 2);
  int jt, ch, nch;
  if (j < 8)        { jt = j;                   ch = 0;            nch = 1; }
  else if (j < 24)  { jt = 8  + ((j - 8) >> 1); ch = (j - 8) & 1;  nch = 2; }
  else if (j < 88)  { jt = 16 + ((j - 24) >> 2); ch = (j - 24) & 3; nch = 4; }
  else              { jt = 32 + ((j - 88) >> 3); ch = (j - 88) & 7; nch = 8; }
  int L = (jt + nch) / nch;           // ceil((jt+1)/nch)
  int c0 = ch * L;
  int c1 = c0 + L; if (c1 > jt + 1) c1 = jt + 1;
  int len = c1 - c0;
  bool direct = (nch == 1);
  int slot = b * 336 + (j - 8);       // valid only when !direct
  int q0 = jt * 64;

  const bf16_t* qb = qg + (size_t)b * SS * HH;
  const bf16_t* kb = kg + (size_t)b * SS * HH;
  const bf16_t* vb = vg + (size_t)b * HH * SS;

  int qrow = q0 + wave * 16 + ml;
  bf16x8 aq0 = *(const bf16x8*)(qb + (size_t)qrow * HH + quad * 8);
  bf16x8 aq1 = *(const bf16x8*)(qb + (size_t)qrow * HH + 32 + quad * 8);

  bf16x8 kreg[2], vreg[2];
  int srl = tid >> 3, scc = tid & 7;
  auto load_kv = [&](int kt) {
#pragma unroll
    for (int i = 0; i < 2; ++i) {
      int r = srl + i * 32;
      kreg[i] = *(const bf16x8*)(kb + (size_t)(kt * 64 + r) * HH + scc * 8);
      vreg[i] = *(const bf16x8*)(vb + (size_t)r * SS + kt * 64 + scc * 8);
    }
  };
  auto store_kv = [&]() {
#pragma unroll
    for (int i = 0; i < 2; ++i) {
      int r = srl + i * 32;
      int off = r * 64 + ((scc ^ (r & 7)) * 8);
      *(bf16x8*)&Kl[off] = kreg[i];
      *(bf16x8*)&Vl[off] = vreg[i];
    }
  };

  f32x4 oa[4];
#pragma unroll
  for (int i = 0; i < 4; ++i) oa[i] = (f32x4){0.f, 0.f, 0.f, 0.f};
  float lr[4] = {0.f, 0.f, 0.f, 0.f};

  load_kv(c0);

  for (int i = 0; i < len; ++i) {
    int kt = c0 + i;
    __syncthreads();                    // prior iter's reads done
    store_kv();
    __syncthreads();                    // staged tile visible
    if (i + 1 < len) load_kv(kt + 1);   // register prefetch hides global latency

    f32x4 sa[4];
#pragma unroll
    for (int nt = 0; nt < 4; ++nt) sa[nt] = (f32x4){0.f, 0.f, 0.f, 0.f};
#pragma unroll
    for (int s = 0; s < 2; ++s) {
      bf16x8 a = s ? aq1 : aq0;
      int rchunk = ((s * 4 + quad) ^ (ml & 7)) * 8;
#pragma unroll
      for (int nt = 0; nt < 4; ++nt) {
        bf16x8 bfr = *(const bf16x8*)&Kl[(nt * 16 + ml) * 64 + rchunk];
        sa[nt] = mfma16(a, bfr, sa[nt]);
      }
    }

    if (kt == jt) {
#pragma unroll
      for (int nt = 0; nt < 4; ++nt) {
        int key = kt * 64 + nt * 16 + ml;
#pragma unroll
        for (int r = 0; r < 4; ++r) {
          int qr = q0 + wave * 16 + quad * 4 + r;
          if (key > qr) sa[nt][r] = -3.38953139e38f;
        }
      }
    }

    // no-max softmax (log2-domain scores bounded; fp32-safe)
#pragma unroll
    for (int r = 0; r < 4; ++r) {
      float p0 = EXP2F(sa[0][r]);
      float p1 = EXP2F(sa[1][r]);
      float p2 = EXP2F(sa[2][r]);
      float p3 = EXP2F(sa[3][r]);
      sa[0][r] = p0; sa[1][r] = p1; sa[2][r] = p2; sa[3][r] = p3;
      lr[r] += (p0 + p1) + (p2 + p3);
    }

    // P: C-layout -> A-layout via per-wave swizzled LDS (same wave, no barrier)
#pragma unroll
    for (int nt = 0; nt < 4; ++nt) {
#pragma unroll
      for (int r = 0; r < 4; ++r) {
        int row = quad * 4 + r;
        int cc = nt * 2 + (ml >> 3);
        Pl[wave][row * 64 + ((cc ^ (row & 7)) * 8) + (ml & 7)] = (bf16_t)sa[nt][r];
      }
    }
#pragma unroll
    for (int s = 0; s < 2; ++s) {
      int rchunk = ((s * 4 + quad) ^ (ml & 7)) * 8;
      bf16x8 pa = *(const bf16x8*)&Pl[wave][ml * 64 + rchunk];
#pragma unroll
      for (int ht = 0; ht < 4; ++ht) {
        bf16x8 bv = *(const bf16x8*)&Vl[(ht * 16 + ml) * 64 + rchunk];
        oa[ht] = mfma16(pa, bv, oa[ht]);
      }
    }
  }

#pragma unroll
  for (int r = 0; r < 4; ++r) {
    float t = lr[r];
    t += __shfl_xor(t, 1);
    t += __shfl_xor(t, 2);
    t += __shfl_xor(t, 4);
    t += __shfl_xor(t, 8);
    lr[r] = t;
  }

  if (direct) {
#pragma unroll
    for (int r = 0; r < 4; ++r) {
      float inv = 1.0f / lr[r];
      int row = q0 + wave * 16 + quad * 4 + r;
#pragma unroll
      for (int ht = 0; ht < 4; ++ht)
        out[((size_t)b * SS + row) * HH + ht * 16 + ml] = oa[ht][r] * inv;
    }
  } else {
    float* po = partO + (size_t)slot * 4096;
#pragma unroll
    for (int r = 0; r < 4; ++r) {
      int row = wave * 16 + quad * 4 + r;
#pragma unroll
      for (int ht = 0; ht < 4; ++ht)
        po[row * 64 + ht * 16 + ml] = oa[ht][r];
      if (ml == 0) lb[slot * 64 + row] = lr[r];
    }
  }
}

// ---------------- kernel 3: combine — 896 WGs (16 rows/WG), f32x4 per thread -------
// 4x the parallelism of the 224-WG version (0.875 -> 3.5 WG/CU): latency-bound
// partO reads overlap across 4x more waves.
__global__ __launch_bounds__(256) void combine(const float* __restrict__ partO,
                                               const float* __restrict__ lb,
                                               float* __restrict__ out) {
  int bid = blockIdx.x;      // 896 = 224 jobs x 4 row-groups
  int rg = bid & 3;
  int jobid = bid >> 2;      // 0..223 = b(4) x jt(8..63)
  int b = jobid / 56;
  int jt = 8 + (jobid - b * 56);
  int nch, jbase;
  if (jt < 16)      { nch = 2; jbase = 8 + 2 * (jt - 8); }
  else if (jt < 32) { nch = 4; jbase = 24 + 4 * (jt - 16); }
  else              { nch = 8; jbase = 88 + 8 * (jt - 32); }
  int base = b * 336 + (jbase - 8);
  int tid = threadIdx.x;
  int row = rg * 16 + (tid >> 4);   // 16 rows per WG
  int seg = tid & 15;               // 16 f32x4 segments = 64 cols

  float l = 0.f;
  f32x4 o = (f32x4){0.f, 0.f, 0.f, 0.f};
  for (int c = 0; c < nch; ++c) {
    l += lb[(base + c) * 64 + row];
    o += *(const f32x4*)(partO + (size_t)(base + c) * 4096 + row * 64 + seg * 4);
  }
  float inv = 1.0f / l;
  *(f32x4*)(out + (((size_t)b * SS) + jt * 64 + row) * HH + seg * 4) = o * inv;
}

// ---------------- host ----------------
extern "C" void kernel_launch(void* const* d_in, const int* in_sizes, int n_in,
                              void* d_out, int out_size, void* d_ws, size_t ws_size,
                              hipStream_t stream) {
  const float* x  = (const float*)d_in[0];
  const float* wq = (const float*)d_in[1];
  const float* wk = (const float*)d_in[2];
  const float* wv = (const float*)d_in[3];
  float* out = (float*)d_out;

  char* wsb = (char*)d_ws;
  bf16_t* wt  = (bf16_t*)wsb;                    // 384 KB
  bf16_t* q   = (bf16_t*)(wsb + 524288);         // 2 MB
  bf16_t* k   = (bf16_t*)(wsb + 2621440);        // 2 MB
  bf16_t* vt  = (bf16_t*)(wsb + 4718592);        // 2 MB
  float*  po  = (float*)(wsb + 6815744);         // 21.5 MB (1344 slots x 16 KB)
  float*  lb  = (float*)(wsb + 28835840);        // 344 KB

  prep_w<<<48, 256, 0, stream>>>(wq, wk, wv, wt);
  gemm_qkv<<<512, 256, 0, stream>>>(x, wt, q, k, vt);
  attn_partial<<<1376, 256, 0, stream>>>(q, k, vt, po, lb, out);
  combine<<<896, 256, 0, stream>>>(po, lb, out);
}

// Round 8
// 137.852 us; speedup vs baseline: 1.5421x; 1.0340x over previous
//
#include <hip/hip_runtime.h>
#include <hip/hip_bf16.h>
#include <math.h>

typedef __bf16 bf16_t;
typedef __bf16 bf16x4 __attribute__((ext_vector_type(4)));
typedef __bf16 bf16x8 __attribute__((ext_vector_type(8)));
typedef float f32x4 __attribute__((ext_vector_type(4)));

constexpr int SS = 4096;
constexpr int DD = 1024;
constexpr int HH = 64;

#if __has_builtin(__builtin_amdgcn_exp2f)
#define EXP2F __builtin_amdgcn_exp2f
#else
#define EXP2F exp2f
#endif

static __device__ __forceinline__ f32x4 mfma16(bf16x8 a, bf16x8 b, f32x4 c) {
  return __builtin_amdgcn_mfma_f32_16x16x32_bf16(a, b, c, 0, 0, 0);
}

// ---------------- kernel 0: W -> Wt bf16 (coalesced via LDS transpose) -------------
__global__ __launch_bounds__(256) void prep_w(const float* __restrict__ wq,
                                              const float* __restrict__ wk,
                                              const float* __restrict__ wv,
                                              bf16_t* __restrict__ wt) {
  __shared__ float ls[64 * 68];
  int tid = threadIdx.x;
  int sel = blockIdx.x >> 4, kb = blockIdx.x & 15, k0 = kb * 64;
  const float* src = (sel == 0) ? wq : ((sel == 1) ? wk : wv);
  int bn = sel * 64;
#pragma unroll
  for (int i = 0; i < 4; ++i) {
    int e = tid + i * 256;
    int r = e >> 4, c4 = (e & 15) * 4;
    *(float4*)&ls[r * 68 + c4] = *(const float4*)(src + (size_t)(k0 + r) * 64 + c4);
  }
  __syncthreads();
#pragma unroll
  for (int j = 0; j < 2; ++j) {
    int e = tid + j * 256;
    int n = e >> 3, kg = e & 7;
    bf16x8 v;
#pragma unroll
    for (int t = 0; t < 8; ++t) v[t] = (bf16_t)ls[(kg * 8 + t) * 68 + n];
    *(bf16x8*)(wt + (size_t)(bn + n) * 1024 + k0 + kg * 8) = v;
  }
}

// ---------------- kernel 1: QKV GEMM — M=32 x N=192, 512 WGs, dbuf (R1-proven) -----
__global__ __launch_bounds__(256) void gemm_qkv(const float* __restrict__ x,
                                                const bf16_t* __restrict__ wt,
                                                bf16_t* __restrict__ qo,
                                                bf16_t* __restrict__ ko,
                                                bf16_t* __restrict__ vto) {
  __shared__ bf16_t xs[2][32 * 64];    // 8 KB dbuf, XOR-swizzled
  __shared__ bf16_t wsh[2][192 * 64];  // 48 KB dbuf, XOR-swizzled
  int tid = threadIdx.x;
  int wave = tid >> 6, lane = tid & 63, quad = lane >> 4, ml = lane & 15;
  int m0 = blockIdx.x * 32;
  int mtile = wave >> 1;          // 0..1 : which 16-row block
  int nt0 = (wave & 1) * 6;       // 0 or 6 : first of six 16-col n-tiles

  f32x4 acc[6];
#pragma unroll
  for (int i = 0; i < 6; ++i) acc[i] = (f32x4){0.f, 0.f, 0.f, 0.f};

  int xrow = tid >> 3, xseg = tid & 7;  // 32 rows x 8 segs of 8 f32
  float4 xr[2];
  bf16x8 wr[6];

  auto load_g = [&](int k0) {
    const float* p = x + (size_t)(m0 + xrow) * DD + k0 + xseg * 8;
    xr[0] = *(const float4*)p;
    xr[1] = *(const float4*)(p + 4);
#pragma unroll
    for (int i = 0; i < 6; ++i) {
      int c = tid + i * 256;
      int r = c >> 3, cc = c & 7;
      wr[i] = *(const bf16x8*)(wt + (size_t)r * DD + k0 + cc * 8);
    }
  };
  auto store_lds = [&](int bf) {
    bf16x8 v0;
    v0[0] = (bf16_t)xr[0].x; v0[1] = (bf16_t)xr[0].y;
    v0[2] = (bf16_t)xr[0].z; v0[3] = (bf16_t)xr[0].w;
    v0[4] = (bf16_t)xr[1].x; v0[5] = (bf16_t)xr[1].y;
    v0[6] = (bf16_t)xr[1].z; v0[7] = (bf16_t)xr[1].w;
    int cc0 = xseg ^ (xrow & 7);
    *(bf16x8*)&xs[bf][xrow * 64 + cc0 * 8] = v0;
#pragma unroll
    for (int i = 0; i < 6; ++i) {
      int c = tid + i * 256;
      int r = c >> 3, cc = c & 7;
      *(bf16x8*)&wsh[bf][r * 64 + ((cc ^ (r & 7)) * 8)] = wr[i];
    }
  };

  load_g(0);
  store_lds(0);
  load_g(64);
  __syncthreads();
  for (int it = 0; it < 16; ++it) {
    int bf = it & 1;
#pragma unroll
    for (int s = 0; s < 2; ++s) {
      int rchunk = ((s * 4 + quad) ^ (ml & 7)) * 8;
      bf16x8 a = *(const bf16x8*)&xs[bf][(mtile * 16 + ml) * 64 + rchunk];
#pragma unroll
      for (int i = 0; i < 6; ++i) {
        bf16x8 bfr = *(const bf16x8*)&wsh[bf][((nt0 + i) * 16 + ml) * 64 + rchunk];
        acc[i] = mfma16(a, bfr, acc[i]);
      }
    }
    if (it < 15) {
      store_lds(1 - bf);
      if (it < 14) load_g((it + 2) * 64);
      __syncthreads();
    }
  }

  int b = m0 >> 12;
  int sr = m0 & 4095;
  const float QSCALE = 0.18033688011112042f;  // log2(e)/sqrt(64)
  bf16_t* vls = (bf16_t*)wsh;                 // overlay: 64 h x 40 stride = 5 KB
#pragma unroll
  for (int i = 0; i < 6; ++i) {
    int col = (wave & 1) * 96 + i * 16 + ml;
#pragma unroll
    for (int r = 0; r < 4; ++r) {
      int lrow = mtile * 16 + quad * 4 + r;
      size_t grow = (size_t)b * SS + sr + lrow;
      if (col < 64) qo[grow * HH + col] = (bf16_t)(acc[i][r] * QSCALE);
      else if (col < 128) ko[grow * HH + (col - 64)] = (bf16_t)(acc[i][r]);
      else vls[(col - 128) * 40 + lrow] = (bf16_t)(acc[i][r]);
    }
  }
  __syncthreads();
  {
    int h = tid >> 2, sg = tid & 3;  // 64 heads x 4 segs of 8 keys
    *(bf16x8*)(vto + ((size_t)b * HH + h) * SS + sr + sg * 8) =
        *(const bf16x8*)&vls[h * 40 + sg * 8];
  }
}

// ---------------- kernel 2: flash attention, swapped QK^T ------------------------
// S computed TRANSPOSED: mfma(A=K_frag, B=Q_frag) -> sa[nt][r] holds
// S^T[key = kt*64 + nt*16 + quad*4 + r][q = ml]. Each lane then owns 4 CONSECUTIVE
// keys of one q-row per nt, so the P transpose to LDS becomes 4x ds_write_b64
// (was 16x ds_write_b16) — the dominant removable LDS cost (~60 cy/wave-tile).
// Row-sum lr is lane-local (scalar); reduce across hi-groups via shfl_xor 16/32.
// PV loop and its LDS read expressions are IDENTICAL to the proven R1 kernel
// (write swizzle at 8-key-chunk granularity XOR (ml&7) matches the read).
// 24 KB LDS, 6 WG/CU. grid 1376 = 4b x 344 jobs, longest-first.
__global__ __launch_bounds__(256) void attn_partial(const bf16_t* __restrict__ qg,
                                                    const bf16_t* __restrict__ kg,
                                                    const bf16_t* __restrict__ vg,
                                                    float* __restrict__ partO,
                                                    float* __restrict__ lb,
                                                    float* __restrict__ out) {
  __shared__ bf16_t Kl[64 * 64];      // 8 KB [key][h] swizzled
  __shared__ bf16_t Vl[64 * 64];      // 8 KB [h][key] swizzled
  __shared__ bf16_t Pl[4][16 * 64];   // 8 KB per-wave scratch [q][key] swizzled
  int tid = threadIdx.x;
  int wave = tid >> 6, lane = tid & 63, quad = lane >> 4, ml = lane & 15;

  int bid = blockIdx.x;
  int b = bid & 3;
  int j = 343 - (bid >> 2);
  int jt, ch, nch;
  if (j < 8)        { jt = j;                   ch = 0;            nch = 1; }
  else if (j < 24)  { jt = 8  + ((j - 8) >> 1); ch = (j - 8) & 1;  nch = 2; }
  else if (j < 88)  { jt = 16 + ((j - 24) >> 2); ch = (j - 24) & 3; nch = 4; }
  else              { jt = 32 + ((j - 88) >> 3); ch = (j - 88) & 7; nch = 8; }
  int L = (jt + nch) / nch;           // ceil((jt+1)/nch)
  int c0 = ch * L;
  int c1 = c0 + L; if (c1 > jt + 1) c1 = jt + 1;
  int len = c1 - c0;
  bool direct = (nch == 1);
  int slot = b * 336 + (j - 8);       // valid only when !direct
  int q0 = jt * 64;

  const bf16_t* qb = qg + (size_t)b * SS * HH;
  const bf16_t* kb = kg + (size_t)b * SS * HH;
  const bf16_t* vb = vg + (size_t)b * HH * SS;

  int qrow = q0 + wave * 16 + ml;     // lane's q-row (B-fragment index)
  bf16x8 aq0 = *(const bf16x8*)(qb + (size_t)qrow * HH + quad * 8);
  bf16x8 aq1 = *(const bf16x8*)(qb + (size_t)qrow * HH + 32 + quad * 8);

  bf16x8 kreg[2], vreg[2];
  int srl = tid >> 3, scc = tid & 7;
  auto load_kv = [&](int kt) {
#pragma unroll
    for (int i = 0; i < 2; ++i) {
      int r = srl + i * 32;
      kreg[i] = *(const bf16x8*)(kb + (size_t)(kt * 64 + r) * HH + scc * 8);
      vreg[i] = *(const bf16x8*)(vb + (size_t)r * SS + kt * 64 + scc * 8);
    }
  };
  auto store_kv = [&]() {
#pragma unroll
    for (int i = 0; i < 2; ++i) {
      int r = srl + i * 32;
      int off = r * 64 + ((scc ^ (r & 7)) * 8);
      *(bf16x8*)&Kl[off] = kreg[i];
      *(bf16x8*)&Vl[off] = vreg[i];
    }
  };

  f32x4 oa[4];
#pragma unroll
  for (int i = 0; i < 4; ++i) oa[i] = (f32x4){0.f, 0.f, 0.f, 0.f};
  float lr = 0.f;                     // lane-local row sum for q = qrow

  load_kv(c0);

  for (int i = 0; i < len; ++i) {
    int kt = c0 + i;
    __syncthreads();                    // prior iter's reads done
    store_kv();
    __syncthreads();                    // staged tile visible
    if (i + 1 < len) load_kv(kt + 1);   // register prefetch hides global latency

    f32x4 sa[4];
#pragma unroll
    for (int nt = 0; nt < 4; ++nt) sa[nt] = (f32x4){0.f, 0.f, 0.f, 0.f};
#pragma unroll
    for (int s = 0; s < 2; ++s) {
      bf16x8 bq = s ? aq1 : aq0;
      int rchunk = ((s * 4 + quad) ^ (ml & 7)) * 8;
#pragma unroll
      for (int nt = 0; nt < 4; ++nt) {
        bf16x8 ak = *(const bf16x8*)&Kl[(nt * 16 + ml) * 64 + rchunk];
        sa[nt] = mfma16(ak, bq, sa[nt]);   // SWAPPED: A=K, B=Q -> S^T
      }
    }

    if (kt == jt) {
#pragma unroll
      for (int nt = 0; nt < 4; ++nt) {
#pragma unroll
        for (int r = 0; r < 4; ++r) {
          int key = kt * 64 + nt * 16 + quad * 4 + r;
          if (key > qrow) sa[nt][r] = -3.38953139e38f;
        }
      }
    }

    // no-max softmax (log2-domain scores bounded; fp32-safe)
#pragma unroll
    for (int nt = 0; nt < 4; ++nt) {
      float p0 = EXP2F(sa[nt][0]);
      float p1 = EXP2F(sa[nt][1]);
      float p2 = EXP2F(sa[nt][2]);
      float p3 = EXP2F(sa[nt][3]);
      sa[nt][0] = p0; sa[nt][1] = p1; sa[nt][2] = p2; sa[nt][3] = p3;
      lr += (p0 + p1) + (p2 + p3);
    }

    // P: lane holds P[q=ml][4 consecutive keys] per nt -> one b64 write each.
    // Chunk cc = (nt*16+quad*4)>>3 = 2nt + (quad>>1); in-chunk off = (quad&1)*4.
    // Same XOR-(ml&7) swizzle at 8-key granularity as the PV read below.
#pragma unroll
    for (int nt = 0; nt < 4; ++nt) {
      bf16x4 pk;
      pk[0] = (bf16_t)sa[nt][0]; pk[1] = (bf16_t)sa[nt][1];
      pk[2] = (bf16_t)sa[nt][2]; pk[3] = (bf16_t)sa[nt][3];
      int cc = 2 * nt + (quad >> 1);
      *(bf16x4*)&Pl[wave][ml * 64 + ((cc ^ (ml & 7)) << 3) + ((quad & 1) << 2)] = pk;
    }
#pragma unroll
    for (int s = 0; s < 2; ++s) {
      int rchunk = ((s * 4 + quad) ^ (ml & 7)) * 8;
      bf16x8 pa = *(const bf16x8*)&Pl[wave][ml * 64 + rchunk];
#pragma unroll
      for (int ht = 0; ht < 4; ++ht) {
        bf16x8 bv = *(const bf16x8*)&Vl[(ht * 16 + ml) * 64 + rchunk];
        oa[ht] = mfma16(pa, bv, oa[ht]);
      }
    }
  }

  // lr: sum across the 4 hi-groups (lanes sharing ml) -> total for q = qrow
  float t = lr;
  t += __shfl_xor(t, 16);
  t += __shfl_xor(t, 32);

  if (direct) {
#pragma unroll
    for (int r = 0; r < 4; ++r) {
      float inv = 1.0f / __shfl(t, quad * 4 + r, 16);  // lr of row quad*4+r
      int row = q0 + wave * 16 + quad * 4 + r;
#pragma unroll
      for (int ht = 0; ht < 4; ++ht)
        out[((size_t)b * SS + row) * HH + ht * 16 + ml] = oa[ht][r] * inv;
    }
  } else {
    float* po = partO + (size_t)slot * 4096;
#pragma unroll
    for (int r = 0; r < 4; ++r) {
      int row = wave * 16 + quad * 4 + r;
#pragma unroll
      for (int ht = 0; ht < 4; ++ht)
        po[row * 64 + ht * 16 + ml] = oa[ht][r];
    }
    if (lane < 16) lb[slot * 64 + wave * 16 + lane] = t;
  }
}

// ---------------- kernel 3: combine (plain sum / sum-l), nch in {2,4,8} ------------
__global__ __launch_bounds__(256) void combine(const float* __restrict__ partO,
                                               const float* __restrict__ lb,
                                               float* __restrict__ out) {
  int bid = blockIdx.x;  // 224 = b(4) x jt(8..63)
  int b = bid / 56;
  int jt = 8 + (bid - b * 56);
  int nch, jbase;
  if (jt < 16)      { nch = 2; jbase = 8 + 2 * (jt - 8); }
  else if (jt < 32) { nch = 4; jbase = 24 + 4 * (jt - 16); }
  else              { nch = 8; jbase = 88 + 8 * (jt - 32); }
  int base = b * 336 + (jbase - 8);
  int tid = threadIdx.x;
  int row = tid >> 2, cb = tid & 3;

  float l = 0.f;
  f32x4 o[4];
#pragma unroll
  for (int jj = 0; jj < 4; ++jj) o[jj] = (f32x4){0.f, 0.f, 0.f, 0.f};
  for (int c = 0; c < nch; ++c) {
    l += lb[(base + c) * 64 + row];
    const f32x4* p = (const f32x4*)(partO + (size_t)(base + c) * 4096 + row * 64 + cb * 16);
#pragma unroll
    for (int jj = 0; jj < 4; ++jj) o[jj] += p[jj];
  }
  float inv = 1.0f / l;
  f32x4* op = (f32x4*)(out + (((size_t)b * SS) + jt * 64 + row) * HH + cb * 16);
#pragma unroll
  for (int jj = 0; jj < 4; ++jj) op[jj] = o[jj] * inv;
}

// ---------------- host ----------------
extern "C" void kernel_launch(void* const* d_in, const int* in_sizes, int n_in,
                              void* d_out, int out_size, void* d_ws, size_t ws_size,
                              hipStream_t stream) {
  const float* x  = (const float*)d_in[0];
  const float* wq = (const float*)d_in[1];
  const float* wk = (const float*)d_in[2];
  const float* wv = (const float*)d_in[3];
  float* out = (float*)d_out;

  char* wsb = (char*)d_ws;
  bf16_t* wt  = (bf16_t*)wsb;                    // 384 KB
  bf16_t* q   = (bf16_t*)(wsb + 524288);         // 2 MB
  bf16_t* k   = (bf16_t*)(wsb + 2621440);        // 2 MB
  bf16_t* vt  = (bf16_t*)(wsb + 4718592);        // 2 MB
  float*  po  = (float*)(wsb + 6815744);         // 21.5 MB (1344 slots x 16 KB)
  float*  lb  = (float*)(wsb + 28835840);        // 344 KB

  prep_w<<<48, 256, 0, stream>>>(wq, wk, wv, wt);
  gemm_qkv<<<512, 256, 0, stream>>>(x, wt, q, k, vt);
  attn_partial<<<1376, 256, 0, stream>>>(q, k, vt, po, lb, out);
  combine<<<224, 256, 0, stream>>>(po, lb, out);
}